// Round 1
// baseline (183.632 us; speedup 1.0000x reference)
//
#include <hip/hip_runtime.h>

#define B_  4
#define Q_  512
#define K_  1024
#define D_  256
#define VD_ 256
#define H_  128
#define TQ  4

// 2*log2(e): tanh(x) = 1 - 2/(exp2(CE*x_q)*exp2(CE*x_k) + 1)
constexpr float CE  = 2.8853900817779268f;
constexpr float L2E = 1.4426950408889634f;

__device__ __forceinline__ float arcp(float x) { return __builtin_amdgcn_rcpf(x); }

// ---------------- prep: m2wv[h] = -2 * w_v[h] ----------------
__global__ void prep_kernel(const float* __restrict__ wv, float* __restrict__ m2wv) {
    int t = threadIdx.x;
    if (t < H_) m2wv[t] = -2.0f * wv[t];
}

// ---------------- projection + exp2 epilogue ----------------
// E[r][h] = exp2(CE * dot(X[r][:], W[:][h])),  X:[rows][256], W:[256][128]
// block: 256 threads -> tile 16 rows x 128 cols; thread: 8 rows x 1 col
__global__ __launch_bounds__(256) void proj_exp_kernel(
    const float* __restrict__ X, const float* __restrict__ W,
    float* __restrict__ E, int rows)
{
    const int tid = threadIdx.x;
    const int c   = tid & 127;
    const int rh  = __builtin_amdgcn_readfirstlane(tid >> 7);  // 0 or 1, wave-uniform
    const int r0  = blockIdx.x * 16 + rh * 8;
    if (r0 >= rows) return;
    const float* Xp = X + (size_t)r0 * D_;

    float acc[8] = {0.f,0.f,0.f,0.f,0.f,0.f,0.f,0.f};
    #pragma unroll 2
    for (int d = 0; d < D_; d += 4) {
        float w0 = W[(d+0)*H_ + c];
        float w1 = W[(d+1)*H_ + c];
        float w2 = W[(d+2)*H_ + c];
        float w3 = W[(d+3)*H_ + c];
        #pragma unroll
        for (int r = 0; r < 8; ++r) {
            float4 x = *(const float4*)(Xp + r*D_ + d);   // uniform addr -> s_load
            acc[r] = fmaf(x.x, w0, acc[r]);
            acc[r] = fmaf(x.y, w1, acc[r]);
            acc[r] = fmaf(x.z, w2, acc[r]);
            acc[r] = fmaf(x.w, w3, acc[r]);
        }
    }
    #pragma unroll
    for (int r = 0; r < 8; ++r)
        E[(size_t)(r0 + r) * H_ + c] = exp2f(acc[r] * CE);
}

// ---------------- fused scores -> softmax -> PV ----------------
// WG = (b, 4 q-rows). Scores chunked over k (256/chunk = 1 k per thread),
// chunks beyond valid_len skipped. S in LDS. Wave w owns q-row w for
// softmax + PV.
#define TERM(ACC, W_, E_, QV) ACC = fmaf(W_, arcp(fmaf(E_, QV, 1.0f)), ACC)
#define QBLK(ACC, QI) { \
    float4 qA = eq4[(QI)*32 + 2*h8]; float4 qB = eq4[(QI)*32 + 2*h8 + 1]; \
    TERM(ACC, wA.x, eA.x, qA.x); TERM(ACC, wA.y, eA.y, qA.y); \
    TERM(ACC, wA.z, eA.z, qA.z); TERM(ACC, wA.w, eA.w, qA.w); \
    TERM(ACC, wB.x, eB.x, qB.x); TERM(ACC, wB.y, eB.y, qB.y); \
    TERM(ACC, wB.z, eB.z, qB.z); TERM(ACC, wB.w, eB.w, qB.w); }
#define PVACC(P, V) { ox = fmaf(P, V.x, ox); oy = fmaf(P, V.y, oy); \
                      oz = fmaf(P, V.z, oz); ow = fmaf(P, V.w, ow); }

__global__ __launch_bounds__(256) void attn_kernel(
    const float* __restrict__ Eq, const float* __restrict__ Ek,
    const float* __restrict__ m2wv, const float* __restrict__ values,
    const int* __restrict__ vlens, float* __restrict__ out)
{
    __shared__ __align__(16) float S[TQ][K_];   // 16 KB
    const int tid = threadIdx.x;
    const int wg  = blockIdx.x;
    const int b   = wg >> 7;              // Q_/TQ = 128 WGs per batch
    const int q0  = (wg & 127) * TQ;
    const int valid = vlens[b];
    const int nch = (valid + 255) >> 8;   // 1..4 chunks of 256 keys
    const int n   = nch << 8;

    const float4* eq4 = (const float4*)(Eq + (size_t)(b*Q_ + q0) * H_); // [TQ][32]
    const float4* wv4 = (const float4*)m2wv;                            // [32]

    // ---- scores ----
    for (int ch = 0; ch < nch; ++ch) {
        const int k = (ch << 8) + tid;
        const float4* ek4 = (const float4*)(Ek + (size_t)(b*K_ + k) * H_); // [32]
        float a0 = 0.f, a1 = 0.f, a2 = 0.f, a3 = 0.f;
        #pragma unroll 4
        for (int h8 = 0; h8 < H_/8; ++h8) {
            float4 eA = ek4[2*h8], eB = ek4[2*h8 + 1];
            float4 wA = wv4[2*h8], wB = wv4[2*h8 + 1];
            QBLK(a0, 0) QBLK(a1, 1) QBLK(a2, 2) QBLK(a3, 3)
        }
        const bool ok = (k < valid);
        S[0][k] = ok ? a0 : -1e30f;
        S[1][k] = ok ? a1 : -1e30f;
        S[2][k] = ok ? a2 : -1e30f;
        S[3][k] = ok ? a3 : -1e30f;
    }
    __syncthreads();

    // ---- softmax: wave w handles q-row w ----
    const int w    = tid >> 6;
    const int lane = tid & 63;
    float m = -3.0e38f;
    for (int i = lane; i < n; i += 64) m = fmaxf(m, S[w][i]);
    #pragma unroll
    for (int off = 32; off > 0; off >>= 1) m = fmaxf(m, __shfl_xor(m, off, 64));
    float l = 0.f;
    for (int i = lane; i < n; i += 64) {
        float p = exp2f((S[w][i] - m) * L2E);
        S[w][i] = p;
        l += p;
    }
    #pragma unroll
    for (int off = 32; off > 0; off >>= 1) l += __shfl_xor(l, off, 64);
    const float invl = arcp(l);

    // ---- PV: thread = (q-row w, cols lane*4..lane*4+3) ----
    float ox = 0.f, oy = 0.f, oz = 0.f, ow = 0.f;
    const float4* vp = (const float4*)(values + (size_t)b * K_ * VD_);
    #pragma unroll 2
    for (int i = 0; i < n; i += 4) {
        float4 p = *(const float4*)&S[w][i];        // LDS broadcast
        const float4* vr = vp + (size_t)i * 64 + lane;
        float4 v0 = vr[0], v1 = vr[64], v2 = vr[128], v3 = vr[192];
        PVACC(p.x, v0) PVACC(p.y, v1) PVACC(p.z, v2) PVACC(p.w, v3)
    }
    float4 o;
    o.x = ox * invl; o.y = oy * invl; o.z = oz * invl; o.w = ow * invl;
    ((float4*)(out + (size_t)(b*Q_ + q0 + w) * VD_))[lane] = o;
}

// ---------------- launch ----------------
extern "C" void kernel_launch(void* const* d_in, const int* in_sizes, int n_in,
                              void* d_out, int out_size, void* d_ws, size_t ws_size,
                              hipStream_t stream) {
    const float* queries = (const float*)d_in[0];
    const float* keys    = (const float*)d_in[1];
    const float* values  = (const float*)d_in[2];
    const int*   vlens   = (const int*)d_in[3];
    const float* W_q     = (const float*)d_in[4];
    const float* W_k     = (const float*)d_in[5];
    const float* w_v     = (const float*)d_in[6];
    float* out = (float*)d_out;
    float* ws  = (float*)d_ws;

    float* Eq   = ws;            // B*Q*H   = 262144 floats
    float* Ek   = ws + 262144;   // B*K*H   = 524288 floats
    float* m2wv = ws + 786432;   // H       = 128 floats

    prep_kernel<<<dim3(1), dim3(128), 0, stream>>>(w_v, m2wv);
    proj_exp_kernel<<<dim3((B_*Q_)/16), dim3(256), 0, stream>>>(queries, W_q, Eq, B_*Q_);
    proj_exp_kernel<<<dim3((B_*K_)/16), dim3(256), 0, stream>>>(keys,    W_k, Ek, B_*K_);
    attn_kernel<<<dim3((B_*Q_)/TQ), dim3(256), 0, stream>>>(Eq, Ek, m2wv, values, vlens, out);
}

// Round 2
// 155.451 us; speedup vs baseline: 1.1813x; 1.1813x over previous
//
#include <hip/hip_runtime.h>

#define B_  4
#define Q_  512
#define K_  1024
#define D_  256
#define VD_ 256
#define H_  128

// tanh(x) = 1 - 2/(1 + e^{2x});  e^{2(q+k)} = Eq*Ek,  Eq = exp2(CE*q)
constexpr float CE  = 2.8853900817779268f;   // 2*log2(e)
constexpr float L2E = 1.4426950408889634f;

__device__ __forceinline__ float arcp(float x) { return __builtin_amdgcn_rcpf(x); }

// ---------------- combined projection: queries->Eq, keys->Ek, + m2wv ----------------
// 8 rows/WG, 256 threads: thread = (col c, row-half rh) computes 4 rows, full-D dot.
// grid = 2048/8 + 4096/8 = 768 WGs.
__global__ __launch_bounds__(256) void proj_kernel(
    const float* __restrict__ Xq, const float* __restrict__ Xk,
    const float* __restrict__ Wq, const float* __restrict__ Wk,
    const float* __restrict__ wv,
    float* __restrict__ Eq, float* __restrict__ Ek, float* __restrict__ m2wv)
{
    const int tid = threadIdx.x;
    const int wg  = blockIdx.x;
    if (wg == 0 && tid < H_) m2wv[tid] = -2.0f * wv[tid];

    const float *X, *W; float* E; int r0;
    if (wg < 256) { X = Xq; W = Wq; E = Eq; r0 = wg * 8; }
    else          { X = Xk; W = Wk; E = Ek; r0 = (wg - 256) * 8; }

    const int c  = tid & 127;
    const int rh = __builtin_amdgcn_readfirstlane(tid >> 7);   // wave-uniform 0/1
    const float* Xp = X + (size_t)(r0 + rh * 4) * D_;

    float acc[4] = {0.f, 0.f, 0.f, 0.f};
    #pragma unroll 4
    for (int d = 0; d < D_; d += 4) {
        float w0 = W[(d+0)*H_ + c];
        float w1 = W[(d+1)*H_ + c];
        float w2 = W[(d+2)*H_ + c];
        float w3 = W[(d+3)*H_ + c];
        #pragma unroll
        for (int r = 0; r < 4; ++r) {
            float4 x = *(const float4*)(Xp + r*D_ + d);   // wave-uniform -> s_load
            acc[r] = fmaf(x.x, w0, acc[r]);
            acc[r] = fmaf(x.y, w1, acc[r]);
            acc[r] = fmaf(x.z, w2, acc[r]);
            acc[r] = fmaf(x.w, w3, acc[r]);
        }
    }
    float* Ep = E + (size_t)(r0 + rh * 4) * H_ + c;
    #pragma unroll
    for (int r = 0; r < 4; ++r) Ep[r * H_] = exp2f(acc[r] * CE);
}

// ---------------- fused scores -> exp -> PV ----------------
// WG = 1024 threads (16 waves), TQ=4 q-rows, grid = B*Q/4 = 512.
// Phase 1: thread k computes exp'd scores for 4 rows -> S (masked -> 0).
// Phase 2: wave w = (row w&3, k-quarter w>>2) accumulates partial O + sum.
// Phase 3: quarter-0 waves combine partials, scale by 1/l, store.
#define TERM(ACC, W_, E_, QV) ACC = fmaf(W_, arcp(fmaf(E_, QV, 1.0f)), ACC)
#define QBLK(ACC, QI) { \
    float4 qA = eq4[(QI)*32 + 2*h8]; float4 qB = eq4[(QI)*32 + 2*h8 + 1]; \
    TERM(ACC, wA.x, eA.x, qA.x); TERM(ACC, wA.y, eA.y, qA.y); \
    TERM(ACC, wA.z, eA.z, qA.z); TERM(ACC, wA.w, eA.w, qA.w); \
    TERM(ACC, wB.x, eB.x, qB.x); TERM(ACC, wB.y, eB.y, qB.y); \
    TERM(ACC, wB.z, eB.z, qB.z); TERM(ACC, wB.w, eB.w, qB.w); }
#define PVACC(P, V) { ox = fmaf(P, V.x, ox); oy = fmaf(P, V.y, oy); \
                      oz = fmaf(P, V.z, oz); ow_ = fmaf(P, V.w, ow_); }

__global__ __launch_bounds__(1024) void attn_kernel(
    const float* __restrict__ Eq, const float* __restrict__ Ek,
    const float* __restrict__ m2wv, const float* __restrict__ values,
    const int* __restrict__ vlens, float* __restrict__ out)
{
    __shared__ __align__(16) float S[4][K_];        // 16 KB  exp'd scores
    __shared__ __align__(16) float OP[3][4][VD_];   // 12 KB  partial O (quarters 1..3)
    __shared__ float SS[3][4];                      // partial sums
    const int tid = threadIdx.x;
    const int wg  = blockIdx.x;
    const int b   = wg & 3;                 // interleave batches across blockIdx
    const int q0  = (wg >> 2) * 4;
    const int valid = vlens[b];
    const int n   = ((valid + 255) >> 8) << 8;      // 256..1024, multiple of 256

    const float4* eq4 = (const float4*)(Eq + (size_t)(b*Q_ + q0) * H_);   // [4][32]
    const float4* wv4 = (const float4*)m2wv;                              // [32]

    // ---- phase 1: scores + exp ----
    const int k = tid;
    if (k < n) {
        const float4* ek4 = (const float4*)(Ek + (size_t)(b*K_ + k) * H_);
        float a0 = 0.f, a1 = 0.f, a2 = 0.f, a3 = 0.f;
        #pragma unroll 4
        for (int h8 = 0; h8 < H_/8; ++h8) {
            float4 eA = ek4[2*h8], eB = ek4[2*h8 + 1];
            float4 wA = wv4[2*h8], wB = wv4[2*h8 + 1];
            QBLK(a0, 0) QBLK(a1, 1) QBLK(a2, 2) QBLK(a3, 3)
        }
        const bool ok = (k < valid);
        S[0][k] = ok ? exp2f(a0 * L2E) : 0.f;   // |score| <= 2*sum|w_v| ~ 18 -> no max-sub needed
        S[1][k] = ok ? exp2f(a1 * L2E) : 0.f;
        S[2][k] = ok ? exp2f(a2 * L2E) : 0.f;
        S[3][k] = ok ? exp2f(a3 * L2E) : 0.f;
    }
    __syncthreads();

    // ---- phase 2: PV with inline sum; wave = (row, quarter) ----
    const int w    = tid >> 6;
    const int lane = tid & 63;
    const int row  = w & 3;
    const int qt   = w >> 2;
    const int i0   = qt << 8;
    const int i1   = min(i0 + 256, n);

    float ox = 0.f, oy = 0.f, oz = 0.f, ow_ = 0.f, l = 0.f;
    const float4* vp = (const float4*)(values + (size_t)b * K_ * VD_);
    for (int i = i0; i < i1; i += 4) {
        float4 p = *(const float4*)&S[row][i];          // LDS broadcast
        const float4* vr = vp + (size_t)i * (VD_/4) + lane;
        float4 v0 = vr[0], v1 = vr[64], v2 = vr[128], v3 = vr[192];
        PVACC(p.x, v0) PVACC(p.y, v1) PVACC(p.z, v2) PVACC(p.w, v3)
        l += (p.x + p.y) + (p.z + p.w);                 // same value in all lanes
    }
    if (qt > 0) {
        *(float4*)&OP[qt-1][row][lane*4] = make_float4(ox, oy, oz, ow_);
        if (lane == 0) SS[qt-1][row] = l;
    }
    __syncthreads();

    // ---- phase 3: combine + store (quarter-0 waves) ----
    if (qt == 0) {
        l += SS[0][row] + SS[1][row] + SS[2][row];
        const float invl = arcp(l);
        float4 p0 = *(const float4*)&OP[0][row][lane*4];
        float4 p1 = *(const float4*)&OP[1][row][lane*4];
        float4 p2 = *(const float4*)&OP[2][row][lane*4];
        float4 o;
        o.x = (ox + p0.x + p1.x + p2.x) * invl;
        o.y = (oy + p0.y + p1.y + p2.y) * invl;
        o.z = (oz + p0.z + p1.z + p2.z) * invl;
        o.w = (ow_ + p0.w + p1.w + p2.w) * invl;
        ((float4*)(out + (size_t)(b*Q_ + q0 + row) * VD_))[lane] = o;
    }
}

// ---------------- launch ----------------
extern "C" void kernel_launch(void* const* d_in, const int* in_sizes, int n_in,
                              void* d_out, int out_size, void* d_ws, size_t ws_size,
                              hipStream_t stream) {
    const float* queries = (const float*)d_in[0];
    const float* keys    = (const float*)d_in[1];
    const float* values  = (const float*)d_in[2];
    const int*   vlens   = (const int*)d_in[3];
    const float* W_q     = (const float*)d_in[4];
    const float* W_k     = (const float*)d_in[5];
    const float* w_v     = (const float*)d_in[6];
    float* out = (float*)d_out;
    float* ws  = (float*)d_ws;

    float* Eq   = ws;            // B*Q*H = 262144 floats
    float* Ek   = ws + 262144;   // B*K*H = 524288 floats
    float* m2wv = ws + 786432;   // H     = 128 floats

    proj_kernel<<<dim3(768), dim3(256), 0, stream>>>(queries, keys, W_q, W_k, w_v, Eq, Ek, m2wv);
    attn_kernel<<<dim3((B_*Q_)/4), dim3(1024), 0, stream>>>(Eq, Ek, m2wv, values, vlens, out);
}